// Round 3
// baseline (149.798 us; speedup 1.0000x reference)
//
#include <hip/hip_runtime.h>
#include <stdint.h>

// out[m,p] = sum_k f32(bits(x[m,k]) + bits(weight[p,k]) - OFFSET) + bias[p]
// m=256, n=512, p=512. Pure VALU workload (uint add on bit patterns -> no MFMA).
//
// R8: attack the two R7 leftovers -- SALU co-saturation and exposed staging.
//  R7 post-mortem: folding OFFSET on the x side cost 16 s_sub/j-step =
//  ~5400 scalar ops/CU vs the 4096-cyc VALU floor on a per-CU shared scalar
//  unit -> SALU co-critical. Half-K staging exposed 64KB (~1170 cyc) up front.
//  Fixes, keeping R7's single-dispatch / wave-k-split / LDS-reduction shell:
//  - v_add3_u32 (VOP3, D=S0+S1+S2): f32(a + b - OFF) is ONE VALU op with
//    -OFF in the single allowed SGPR operand. No fold needed anywhere; SALU
//    drops to loop control. Requires a in VGPR -> x staged raw into LDS
//    (16KB contiguous, global_load_lds, no transform) and read via
//    uniform-address ds_read_b128 (same addr across lanes = broadcast,
//    conflict-free). Forced via inline asm so the compiler can't split it
//    into 2 adds + unencodable literal.
//    Inner loop/step: 1 swizzled b128 + 4 broadcast b128 + 16 v_add3 +
//    16 v_add_f32 = exactly 2 VALU/element (4096 cyc/CU floor). LDS pipe
//    per step-window: 8 wide (64cyc) + 32 bcast (~32cyc) < 128cyc cap.
//  - 4-quarter pipelined w staging: Bs[4][64][128] quarter-major so each
//    1KB gll call spans 2 contiguous 512B row-segments. Issue q(h+1) right
//    after the barrier, compute(h) (1024 cyc/SIMD) hides its ~585cyc
//    delivery; only q0+x (~700 cyc, 0.3us) is exposed vs R7's 1170.
//  - same measured-0-conflict swizzle family (R5/R7): storage granule
//    g^(row&7); compute reads (j^rot), rot=lane&7 -> consecutive 8 lanes
//    hit 8 distinct granules = 32 distinct banks. Broadcast x-reads are
//    bank-free by definition.
//
// Measurement context: ~60us of dur_us is fixed harness cost (268MB ws
// re-poison = 40us at 84% HBM peak). Controllable = this one kernel:
// R7 ~3us, target ~2.5us (VALU floor 1.71us + exposed stage + tails).

#define OFFSET_FP32 1064828928u

constexpr int M = 256;
constexpr int N = 512;
constexpr int P = 512;

constexpr int BM = 8;    // m rows per block
constexpr int BP = 64;   // p cols per block
constexpr int TM = 4;    // m rows per thread
constexpr int NQ = 4;    // k quarters
constexpr int QK = 128;  // k per quarter

// one lmul element: f32(a + b + (-OFF)), a,b VGPR, negOff SGPR (VOP3-legal)
__device__ __forceinline__ float lmul1(uint32_t a, uint32_t b, uint32_t negOff) {
    uint32_t u;
    asm("v_add3_u32 %0, %1, %2, %3" : "=v"(u) : "v"(a), "v"(b), "s"(negOff));
    return __uint_as_float(u);
}

__global__ __launch_bounds__(512) void lmul_linear_kernel(
    const uint32_t* __restrict__ xb,   // [M][N] bit patterns of x
    const uint32_t* __restrict__ wb,   // [P][N] bit patterns of weight
    const float*    __restrict__ bias, // [P]
    float*          __restrict__ out)  // [M][P]
{
    __shared__ uint32_t Bs[NQ][BP][QK];   // 128 KB w tile, quarter-major
    __shared__ uint32_t Xs[BM * N];       // 16 KB raw x tile
    __shared__ float    Red[4][BM][BP];   // 8 KB k-group partials

    const int tid  = threadIdx.x;
    const int lane = tid & 63;                                  // = p_local
    const int wq   = __builtin_amdgcn_readfirstlane(tid >> 6);  // wave 0..7
    const int ks   = wq & 3;   // k-group
    const int mq   = wq >> 2;  // row half

    const int p0 = blockIdx.y * BP;

    // ---- stage w quarter h: 32KB = 32 x 1KB gll calls, 4 per wave; call i
    //      spans rows {wq*8+2i, +1} (contiguous 512B segments in Bs[h]).
    //      Swizzle rides on the per-lane GLOBAL src granule (both-sides rule). --
    auto stage_w = [&](int h) {
        #pragma unroll
        for (int i = 0; i < 4; ++i) {
            const int row = wq * 8 + i * 2 + (lane >> 5);
            const int g   = lane & 31;                    // 16B granule in segment
            const uint32_t* src = wb + (size_t)(p0 + row) * N + h * QK
                                     + (size_t)((g ^ (row & 7)) * 4);
            uint32_t* dst = &Bs[h][wq * 8 + i * 2][0];    // wave-uniform base
            __builtin_amdgcn_global_load_lds(
                (const __attribute__((address_space(1))) uint32_t*)src,
                (__attribute__((address_space(3))) uint32_t*)dst,
                16, 0, 0);
        }
    };

    // ---- stage x: 16KB contiguous raw copy, 16 x 1KB gll calls, 2 per wave --
    {
        const uint32_t* xsrc = xb + (size_t)blockIdx.x * BM * N;
        stage_w(0);                       // biggest-latency first
        #pragma unroll
        for (int i = 0; i < 2; ++i) {
            const int call = wq * 2 + i;
            const uint32_t* src = xsrc + call * 256 + lane * 4;
            uint32_t* dst = &Xs[call * 256];
            __builtin_amdgcn_global_load_lds(
                (const __attribute__((address_space(1))) uint32_t*)src,
                (__attribute__((address_space(3))) uint32_t*)dst,
                16, 0, 0);
        }
    }

    float acc[TM][4] = {};
    const int      rot     = lane & 7;
    const uint32_t NEG_OFF = 0u - OFFSET_FP32;   // uniform -> SGPR

    __syncthreads();   // vmcnt(0): q0 + x resident

    #pragma unroll
    for (int h = 0; h < NQ; ++h) {
        if (h + 1 < NQ) stage_w(h + 1);   // async, hides under compute(h)

        const uint32_t* brow = &Bs[h][lane][ks * 32];
        const uint32_t* xq   = &Xs[(mq * TM) * N + h * QK + ks * 32];

        // 8 steps x (1 swizzled b128 + 4 broadcast b128 + 16 add3 + 16 fadd)
        #pragma unroll
        for (int j = 0; j < 8; ++j) {
            const uint4 b  = *(const uint4*)&brow[(j ^ rot) * 4];
            const uint4 a0 = *(const uint4*)&xq[0 * N + j * 4];  // uniform addr
            const uint4 a1 = *(const uint4*)&xq[1 * N + j * 4];  //  -> broadcast
            const uint4 a2 = *(const uint4*)&xq[2 * N + j * 4];
            const uint4 a3 = *(const uint4*)&xq[3 * N + j * 4];
            acc[0][0] += lmul1(a0.x, b.x, NEG_OFF);
            acc[0][1] += lmul1(a0.y, b.y, NEG_OFF);
            acc[0][2] += lmul1(a0.z, b.z, NEG_OFF);
            acc[0][3] += lmul1(a0.w, b.w, NEG_OFF);
            acc[1][0] += lmul1(a1.x, b.x, NEG_OFF);
            acc[1][1] += lmul1(a1.y, b.y, NEG_OFF);
            acc[1][2] += lmul1(a1.z, b.z, NEG_OFF);
            acc[1][3] += lmul1(a1.w, b.w, NEG_OFF);
            acc[2][0] += lmul1(a2.x, b.x, NEG_OFF);
            acc[2][1] += lmul1(a2.y, b.y, NEG_OFF);
            acc[2][2] += lmul1(a2.z, b.z, NEG_OFF);
            acc[2][3] += lmul1(a2.w, b.w, NEG_OFF);
            acc[3][0] += lmul1(a3.x, b.x, NEG_OFF);
            acc[3][1] += lmul1(a3.y, b.y, NEG_OFF);
            acc[3][2] += lmul1(a3.z, b.z, NEG_OFF);
            acc[3][3] += lmul1(a3.w, b.w, NEG_OFF);
        }

        if (h + 1 < NQ) __syncthreads();  // drains q(h+1) + makes it visible
    }

    // ---- per-output 4-way k-group reduction in LDS, then one plain store ----
    #pragma unroll
    for (int r = 0; r < TM; ++r)
        Red[ks][mq * TM + r][lane] =
            (acc[r][0] + acc[r][1]) + (acc[r][2] + acc[r][3]);
    __syncthreads();

    const int rr = tid >> 6;          // 0..7: local output row
    const int p  = p0 + lane;
    const float s = (Red[0][rr][lane] + Red[1][rr][lane])
                  + (Red[2][rr][lane] + Red[3][rr][lane]);
    out[(size_t)(blockIdx.x * BM + rr) * P + p] = s + bias[p];
}

extern "C" void kernel_launch(void* const* d_in, const int* in_sizes, int n_in,
                              void* d_out, int out_size, void* d_ws, size_t ws_size,
                              hipStream_t stream) {
    const uint32_t* xb   = (const uint32_t*)d_in[0];  // x: (256,512) f32 bits
    const uint32_t* wb   = (const uint32_t*)d_in[1];  // weight: (512,512) f32 bits
    const float*    bias = (const float*)d_in[2];     // (512,)
    float*          out  = (float*)d_out;             // (256,512) f32

    // single dispatch: every output written exactly once by its owning block
    dim3 grid(M / BM, P / BP);  // (32, 8) = 256 blocks = 1 per CU
    dim3 block(512);            // 8 waves = 2 waves/SIMD
    lmul_linear_kernel<<<grid, block, 0, stream>>>(xb, wb, bias, out);
}

// Round 4
// 64.080 us; speedup vs baseline: 2.3377x; 2.3377x over previous
//
#include <hip/hip_runtime.h>
#include <stdint.h>

// out[m,p] = sum_k f32(bits(x[m,k]) + bits(weight[p,k]) - OFFSET) + bias[p]
// m=256, n=512, p=512. Pure VALU workload (uint add on bit patterns -> no MFMA).
//
// R9 = R7 shell + R5's staging-time OFFSET fold (kills R7's SALU co-limit).
//  R8 post-mortem (149us): full unroll + 512 inline-asm lmuls + LDS-broadcast
//  x exploded register pressure -> 213MB scratch traffic (FETCH 74MB / WRITE
//  139MB), VALUBusy 3.6%. Reverted wholesale.
//  R7 post-mortem (64.13): folding OFFSET on the x side = 16 s_sub/j-step =
//  ~5400 SALU-ALU ops/CU vs 4096-cyc VALU floor -> SALU co-critical.
//  R9 changes vs R7 (shell, grid, k-split, reduction identical):
//  - w staged by REGISTER (global_load_dwordx4 -> v_subrev offset ->
//    ds_write_b128 to swizzled address) instead of global_load_lds. The
//    fold costs ~128 VALU/thread (~3% of floor) and removes ALL per-element
//    SALU: inner loop is exactly 16 v_add_u32 + 16 v_add_f32 per step.
//  - ds_write side: each wave writes one full 1KB row-segment per iter,
//    lane -> storage granule (lane ^ (row&7)) = permutation of a contiguous
//    1KB block -> conflict-free. Read side BYTE-IDENTICAL to R7's pattern
//    (storage granule ks*16+(j^rot), rot=lane&7), same family R5 measured
//    at SQ_LDS_BANK_CONFLICT==0.
//  - staging pipeline kept: half-B global loads issued BEFORE the first
//    barrier, ds_writes placed after compute(0). __syncthreads would drain
//    vmcnt(0) and expose them (the R7 gll trick relied on the drain landing
//    after compute(0)), so barriers are s_waitcnt lgkmcnt(0) + s_barrier:
//    cross-wave correctness only needs the LDS writes drained; the in-flight
//    w1 globals are wave-private. "memory" clobber pins load order.
//  - x path: R7's wave-uniform s_load_dwordx4 scalar path, now WITHOUT any
//    subtract. SMEM ops ride lgkmcnt, not the scalar ALU.
//
// Measurement context: ~60us of dur_us is fixed harness cost (268MB ws
// re-poison = 40us at 84% HBM peak). Controllable = this one kernel:
// R7 ~2.8us, target ~2.3us (VALU floor 1.71us + exposed half-A + tails).

#define OFFSET_FP32 1064828928u

constexpr int M = 256;
constexpr int N = 512;
constexpr int P = 512;

constexpr int BM = 8;    // m rows per block
constexpr int BP = 64;   // p cols per block
constexpr int TM = 4;    // m rows per thread

__global__ __launch_bounds__(512) void lmul_linear_kernel(
    const uint32_t* __restrict__ xb,   // [M][N] bit patterns of x
    const uint32_t* __restrict__ wb,   // [P][N] bit patterns of weight
    const float*    __restrict__ bias, // [P]
    float*          __restrict__ out)  // [M][P]
{
    __shared__ uint32_t Bs[BP][N];        // 64 x 512 dwords = 128 KB
    __shared__ float    Red[4][BM][BP];   // k-group partials, 8 KB

    const int tid  = threadIdx.x;
    const int lane = tid & 63;                                     // = p_local
    const int wq   = __builtin_amdgcn_readfirstlane(tid >> 6);     // wave 0..7
    const int ks   = wq & 3;   // k-group
    const int mq   = wq >> 2;  // row half

    const int p0 = blockIdx.y * BP;
    const int m0 = blockIdx.x * BM + mq * TM;

    // ---- reg-staging of w half h (dwords h*256..h*256+255 of each row).
    //      Wave wq covers rows wq*8..wq*8+7, one full 1KB row-segment per
    //      iter (64 lanes x 16B). Loads coalesced; fold OFFSET in VGPRs;
    //      ds_write_b128 to the swizzled granule (permutation of the 1KB
    //      segment -> conflict-free). ----
    auto stage_load = [&](int h, uint4* r) {
        #pragma unroll
        for (int i = 0; i < 8; ++i) {
            const int row = wq * 8 + i;
            r[i] = *(const uint4*)(wb + (size_t)(p0 + row) * N + h * 256 + lane * 4);
        }
    };
    auto stage_write = [&](int h, uint4* r) {
        #pragma unroll
        for (int i = 0; i < 8; ++i) {
            const int row = wq * 8 + i;
            uint4 v = r[i];
            v.x -= OFFSET_FP32; v.y -= OFFSET_FP32;   // v_subrev, VALU (~3% floor)
            v.z -= OFFSET_FP32; v.w -= OFFSET_FP32;
            *(uint4*)&Bs[row][h * 256 + ((lane ^ (row & 7)) * 4)] = v;
        }
    };

    float acc[TM][4] = {};
    const int rot = lane & 7;

    const uint32_t* xr0 = xb + (size_t)(m0 + 0) * N;
    const uint32_t* xr1 = xb + (size_t)(m0 + 1) * N;
    const uint32_t* xr2 = xb + (size_t)(m0 + 2) * N;
    const uint32_t* xr3 = xb + (size_t)(m0 + 3) * N;

    // ---- compute stripe of half h for this k-group: 16 steps x
    //      (1 ds_read_b128 + 4 uniform uint4 s_loads + 32 VALU) ----
    auto compute = [&](int h) {
        const uint32_t* brow = &Bs[lane][(h * 64 + ks * 16) * 4];
        const int xoff = h * 256 + ks * 64;
        #pragma unroll 8
        for (int j = 0; j < 16; ++j) {
            const uint4 b  = *(const uint4*)&brow[(j ^ rot) * 4];
            const uint4 a0 = *(const uint4*)(xr0 + xoff + j * 4);  // scalar path
            const uint4 a1 = *(const uint4*)(xr1 + xoff + j * 4);
            const uint4 a2 = *(const uint4*)(xr2 + xoff + j * 4);
            const uint4 a3 = *(const uint4*)(xr3 + xoff + j * 4);
            acc[0][0] += __uint_as_float(a0.x + b.x);
            acc[0][1] += __uint_as_float(a0.y + b.y);
            acc[0][2] += __uint_as_float(a0.z + b.z);
            acc[0][3] += __uint_as_float(a0.w + b.w);
            acc[1][0] += __uint_as_float(a1.x + b.x);
            acc[1][1] += __uint_as_float(a1.y + b.y);
            acc[1][2] += __uint_as_float(a1.z + b.z);
            acc[1][3] += __uint_as_float(a1.w + b.w);
            acc[2][0] += __uint_as_float(a2.x + b.x);
            acc[2][1] += __uint_as_float(a2.y + b.y);
            acc[2][2] += __uint_as_float(a2.z + b.z);
            acc[2][3] += __uint_as_float(a2.w + b.w);
            acc[3][0] += __uint_as_float(a3.x + b.x);
            acc[3][1] += __uint_as_float(a3.y + b.y);
            acc[3][2] += __uint_as_float(a3.z + b.z);
            acc[3][3] += __uint_as_float(a3.w + b.w);
        }
    };

    // LDS-visibility-only barrier: drain ds/smem (lgkm) but NOT the in-flight
    // wave-private global loads (vmcnt) -- __syncthreads would drain vmcnt(0)
    // and expose the half-B staging loads.
    auto lds_barrier = [&]() {
        asm volatile("s_waitcnt lgkmcnt(0)" ::: "memory");
        __builtin_amdgcn_s_barrier();
        __builtin_amdgcn_sched_barrier(0);
    };

    uint4 w0[8], w1[8];
    stage_load(0, w0);
    stage_write(0, w0);        // vmcnt waits inserted here per-register
    stage_load(1, w1);         // issue; delivery rides under compute(0)
    lds_barrier();             // half A visible to all waves

    compute(0);
    stage_write(1, w1);        // w1 arrived during compute(0)
    lds_barrier();             // half B visible

    compute(1);

    // ---- per-output 4-way k-group reduction in LDS, then one plain store ----
    #pragma unroll
    for (int r = 0; r < TM; ++r)
        Red[ks][mq * TM + r][lane] =
            (acc[r][0] + acc[r][1]) + (acc[r][2] + acc[r][3]);
    __syncthreads();

    const int rr = tid >> 6;          // 0..7: local output row
    const int p  = p0 + lane;
    const float s = (Red[0][rr][lane] + Red[1][rr][lane])
                  + (Red[2][rr][lane] + Red[3][rr][lane]);
    out[(size_t)(blockIdx.x * BM + rr) * P + p] = s + bias[p];
}

extern "C" void kernel_launch(void* const* d_in, const int* in_sizes, int n_in,
                              void* d_out, int out_size, void* d_ws, size_t ws_size,
                              hipStream_t stream) {
    const uint32_t* xb   = (const uint32_t*)d_in[0];  // x: (256,512) f32 bits
    const uint32_t* wb   = (const uint32_t*)d_in[1];  // weight: (512,512) f32 bits
    const float*    bias = (const float*)d_in[2];     // (512,)
    float*          out  = (float*)d_out;             // (256,512) f32

    // single dispatch: every output written exactly once by its owning block
    dim3 grid(M / BM, P / BP);  // (32, 8) = 256 blocks = 1 per CU
    dim3 block(512);            // 8 waves = 2 waves/SIMD
    lmul_linear_kernel<<<grid, block, 0, stream>>>(xb, wb, bias, out);
}

// Round 5
// 63.393 us; speedup vs baseline: 2.3630x; 1.0108x over previous
//
#include <hip/hip_runtime.h>
#include <stdint.h>

// out[m,p] = sum_k f32(bits(x[m,k]) + bits(weight[p,k]) - OFFSET) + bias[p]
// m=256, n=512, p=512. Pure VALU workload (uint add on bit patterns -> no MFMA).
//
// R10 = R9 shell + quarter-granular staging rotation (hide ALL w staging).
//  R9 post-mortem (64.08, neutral): SALU fold fix didn't pay; the itemized
//  remaining overhead is staging exposure: initial 64KB half-A (~1170 cyc
//  at 56B/cyc/CU from L2) + half-B ds_writes (~512 cyc) serialized between
//  compute(0) and the barrier. VALU floor is 4096 cyc/CU.
//  R10 changes (shell, grid, wave-k-split, swizzle, reduction identical):
//  - Bs reshaped [4][64][128] quarter-major. Only q0 staged before the
//    first barrier: initial exposure 64KB -> 32KB (~585 cyc).
//  - quarter q+1's ds_writes target Bs[q+1], which nobody reads during
//    compute(q) -> interleave them INTO compute(q), one ds_write_b128
//    after each odd j-step. vmcnt deps are stale (loads issued >=585 cyc
//    earlier), LDS pipe has slack, so the pre-barrier lgkm drain finds
//    them retired: mid-kernel write exposure ~0 (was 512 cyc).
//  - loads for q+2 issued waitless at the top of compute(q); two 16-VGPR
//    staging buffers rotate (ra/rb). NOT an R8 rerun: 2 buffers, unroll-8
//    loop body, no inline-asm ALU -> pressure ~= R9 (128 VGPR, no scratch).
//  - barriers remain lgkmcnt(0)+s_barrier (LDS-visibility only) so the
//    in-flight wave-private global loads are never drained by a barrier.
//  Overhead model: 1682 -> ~650 cyc; kernel ~2.6 -> ~2.15us.
//
// Measurement context: ~60us of dur_us is fixed harness cost (268MB ws
// re-poison = 40us at 84% HBM peak). Controllable = this one kernel.

#define OFFSET_FP32 1064828928u

constexpr int M = 256;
constexpr int N = 512;
constexpr int P = 512;

constexpr int BM = 8;    // m rows per block
constexpr int BP = 64;   // p cols per block
constexpr int TM = 4;    // m rows per thread
constexpr int NQ = 4;    // k quarters
constexpr int QK = 128;  // dwords per quarter per row

__global__ __launch_bounds__(512) void lmul_linear_kernel(
    const uint32_t* __restrict__ xb,   // [M][N] bit patterns of x
    const uint32_t* __restrict__ wb,   // [P][N] bit patterns of weight
    const float*    __restrict__ bias, // [P]
    float*          __restrict__ out)  // [M][P]
{
    __shared__ uint32_t Bs[NQ][BP][QK];   // 128 KB, quarter-major
    __shared__ float    Red[4][BM][BP];   // 8 KB k-group partials

    const int tid  = threadIdx.x;
    const int lane = tid & 63;                                     // = p_local
    const int wq   = __builtin_amdgcn_readfirstlane(tid >> 6);     // wave 0..7
    const int ks   = wq & 3;   // k-group
    const int mq   = wq >> 2;  // row half

    const int p0 = blockIdx.y * BP;
    const int m0 = blockIdx.x * BM + mq * TM;

    const int g    = lane & 31;   // 16B granule within a 512B row-quarter
    const int rsel = lane >> 5;   // each wave iter covers 2 rows

    // ---- quarter q: wave wq covers rows wq*8..wq*8+7, 4 iters x 2 rows.
    //      Loads plain coalesced (512B per row-quarter); swizzle applied at
    //      the ds_write address: granule g stored at g^(row&7) -> write is a
    //      permutation of a contiguous 1KB region = conflict-free b128. ----
    auto qload = [&](int q, uint4* r) {
        #pragma unroll
        for (int i = 0; i < 4; ++i) {
            const int row = wq * 8 + i * 2 + rsel;
            r[i] = *(const uint4*)(wb + (size_t)(p0 + row) * N + q * QK + g * 4);
        }
    };
    auto qwrite1 = [&](int q, uint4 v, int i) {   // one fold+write
        const int row = wq * 8 + i * 2 + rsel;
        v.x -= OFFSET_FP32; v.y -= OFFSET_FP32;
        v.z -= OFFSET_FP32; v.w -= OFFSET_FP32;
        *(uint4*)&Bs[q][row][(g ^ (row & 7)) * 4] = v;
    };

    float acc[TM][4] = {};
    const int rot = lane & 7;

    const uint32_t* xr0 = xb + (size_t)(m0 + 0) * N;
    const uint32_t* xr1 = xb + (size_t)(m0 + 1) * N;
    const uint32_t* xr2 = xb + (size_t)(m0 + 2) * N;
    const uint32_t* xr3 = xb + (size_t)(m0 + 3) * N;

    // ---- compute quarter q for this k-group: 8 steps x (1 ds_read_b128 +
    //      4 uniform uint4 s_loads + 32 VALU); if feeding, one ds_write_b128
    //      of quarter qn after each odd step (hidden under the VALU). ----
    auto computeq = [&](int q, bool feed, int qn, uint4* r) {
        const uint32_t* brow = &Bs[q][lane][ks * 32];
        const int xoff = q * QK + ks * 32;
        #pragma unroll
        for (int j = 0; j < 8; ++j) {
            const uint4 b  = *(const uint4*)&brow[(j ^ rot) * 4];
            const uint4 a0 = *(const uint4*)(xr0 + xoff + j * 4);  // scalar path
            const uint4 a1 = *(const uint4*)(xr1 + xoff + j * 4);
            const uint4 a2 = *(const uint4*)(xr2 + xoff + j * 4);
            const uint4 a3 = *(const uint4*)(xr3 + xoff + j * 4);
            acc[0][0] += __uint_as_float(a0.x + b.x);
            acc[0][1] += __uint_as_float(a0.y + b.y);
            acc[0][2] += __uint_as_float(a0.z + b.z);
            acc[0][3] += __uint_as_float(a0.w + b.w);
            acc[1][0] += __uint_as_float(a1.x + b.x);
            acc[1][1] += __uint_as_float(a1.y + b.y);
            acc[1][2] += __uint_as_float(a1.z + b.z);
            acc[1][3] += __uint_as_float(a1.w + b.w);
            acc[2][0] += __uint_as_float(a2.x + b.x);
            acc[2][1] += __uint_as_float(a2.y + b.y);
            acc[2][2] += __uint_as_float(a2.z + b.z);
            acc[2][3] += __uint_as_float(a2.w + b.w);
            acc[3][0] += __uint_as_float(a3.x + b.x);
            acc[3][1] += __uint_as_float(a3.y + b.y);
            acc[3][2] += __uint_as_float(a3.z + b.z);
            acc[3][3] += __uint_as_float(a3.w + b.w);
            if (feed && (j & 1)) qwrite1(qn, r[j >> 1], j >> 1);
        }
    };

    // LDS-visibility-only barrier: drain lgkm (ds + smem) but NOT the
    // in-flight wave-private global staging loads (vmcnt).
    auto lds_barrier = [&]() {
        asm volatile("s_waitcnt lgkmcnt(0)" ::: "memory");
        __builtin_amdgcn_s_barrier();
        __builtin_amdgcn_sched_barrier(0);
    };

    uint4 ra[4], rb[4];
    qload(0, ra);
    #pragma unroll
    for (int i = 0; i < 4; ++i) qwrite1(0, ra[i], i);  // vmcnt waits here
    qload(1, rb);              // q1 in flight; delivery rides under compute(0)
    lds_barrier();             // q0 visible

    qload(2, ra);              // waitless issue
    computeq(0, true, 1, rb);  // q1 writes interleaved, hidden
    lds_barrier();             // q1 visible

    qload(3, rb);
    computeq(1, true, 2, ra);
    lds_barrier();             // q2 visible

    computeq(2, true, 3, rb);
    lds_barrier();             // q3 visible

    computeq(3, false, 0, nullptr);

    // ---- per-output 4-way k-group reduction in LDS, then one plain store ----
    #pragma unroll
    for (int r = 0; r < TM; ++r)
        Red[ks][mq * TM + r][lane] =
            (acc[r][0] + acc[r][1]) + (acc[r][2] + acc[r][3]);
    __syncthreads();

    const int rr = tid >> 6;          // 0..7: local output row
    const int p  = p0 + lane;
    const float s = (Red[0][rr][lane] + Red[1][rr][lane])
                  + (Red[2][rr][lane] + Red[3][rr][lane]);
    out[(size_t)(blockIdx.x * BM + rr) * P + p] = s + bias[p];
}

extern "C" void kernel_launch(void* const* d_in, const int* in_sizes, int n_in,
                              void* d_out, int out_size, void* d_ws, size_t ws_size,
                              hipStream_t stream) {
    const uint32_t* xb   = (const uint32_t*)d_in[0];  // x: (256,512) f32 bits
    const uint32_t* wb   = (const uint32_t*)d_in[1];  // weight: (512,512) f32 bits
    const float*    bias = (const float*)d_in[2];     // (512,)
    float*          out  = (float*)d_out;             // (256,512) f32

    // single dispatch: every output written exactly once by its owning block
    dim3 grid(M / BM, P / BP);  // (32, 8) = 256 blocks = 1 per CU
    dim3 block(512);            // 8 waves = 2 waves/SIMD
    lmul_linear_kernel<<<grid, block, 0, stream>>>(xb, wb, bias, out);
}